// Round 4
// baseline (170.502 us; speedup 1.0000x reference)
//
#include <hip/hip_runtime.h>
#include <hip/hip_cooperative_groups.h>

#define KC 32
#define CH 16
#define NB 8
#define NPI (512*512)
#define TPB 512               // 8 waves
#define NBLK 256              // 1 block per CU -> cooperative launch always fits
#define BPI (NBLK/NB)         // 32 blocks per image
#define PPB (NPI/BPI)         // 8192 px per block
#define SPW (PPB/8)           // 1024 px per wave
#define SCH (SPW/64)          // 16 chunks of 64 px

// ws layout (floats); every cell written before read each call -> no pre-zero
#define WS_PART 0                          // [256][544] per-block segsum partials
#define WS_CEN (WS_PART + NBLK*544)        // [8][16][32] centroids [c][k]
#define WS_PR  (WS_CEN + NB*CH*KC)         // [8] push + 1e-4*reg
#define WS_PLP (WS_PR + NB)                // [256] per-block pull partials

typedef float f32x16 __attribute__((ext_vector_type(16)));
typedef short short8 __attribute__((ext_vector_type(8)));

__device__ __forceinline__ unsigned short f2bf(float x) {
  unsigned u = __builtin_bit_cast(unsigned, x);
  u += 0x7FFFu + ((u >> 16) & 1u);          // RNE to bf16
  return (unsigned short)(u >> 16);
}
__device__ __forceinline__ unsigned packbf(float lo, float hi) {
  return (unsigned)f2bf(lo) | ((unsigned)f2bf(hi) << 16);
}

__global__ __launch_bounds__(TPB, 2) void fused_kernel(
    const float4* __restrict__ embv, const int* __restrict__ lab,
    float* __restrict__ ws, float* __restrict__ out) {
  __shared__ unsigned smem[8][8][68];   // per-wave bf16x2 staging, stride-68 pad
  __shared__ int      slab[8][64];
  __shared__ float    sred[8][KC * 17];
  __shared__ float    pcent[CH * KC];   // phase C centroids [c][k]
  __shared__ float    sums_s[KC * 17];  // phase B
  __shared__ float    cs[CH * KC];      // phase B centroids [c][k]
  __shared__ float    validf[KC];
  __shared__ float    red8[8];

  const int t = threadIdx.x, w = t >> 6, l = t & 63;
  const int h = l >> 5;                 // k-half of MFMA operands
  const int m = l & 31;                 // A row (label) / B col (channel|count)
  const int b = blockIdx.x / BPI, blk = blockIdx.x % BPI;
  const size_t base = (size_t)b * NPI + (size_t)blk * PPB + (size_t)w * SPW;

  cooperative_groups::grid_group grid = cooperative_groups::this_grid();

  f32x16 acc;
  #pragma unroll
  for (int i = 0; i < 16; ++i) acc[i] = 0.f;

  unsigned upx[SCH][8];                 // retained bf16x2 pixels (static idx via unroll)
  unsigned labp[4] = {0u, 0u, 0u, 0u};  // 16 labels, 8 bits each

  float4 c0, c1, c2, c3; int cl;
  {
    const float4* ep = embv + (base + l) * 4;
    c0 = ep[0]; c1 = ep[1]; c2 = ep[2]; c3 = ep[3];
    cl = lab[base + l];
  }

  // ---------------- Phase A: segment-sum via onehot^T * emb (MFMA) ----------------
  #pragma unroll
  for (int ch = 0; ch < SCH; ++ch) {
    const unsigned p0 = packbf(c0.x, c0.y), p1 = packbf(c0.z, c0.w);
    const unsigned p2 = packbf(c1.x, c1.y), p3 = packbf(c1.z, c1.w);
    const unsigned p4 = packbf(c2.x, c2.y), p5 = packbf(c2.z, c2.w);
    const unsigned p6 = packbf(c3.x, c3.y), p7 = packbf(c3.z, c3.w);
    smem[w][0][l] = p0; smem[w][1][l] = p1; smem[w][2][l] = p2; smem[w][3][l] = p3;
    smem[w][4][l] = p4; smem[w][5][l] = p5; smem[w][6][l] = p6; smem[w][7][l] = p7;
    slab[w][l] = cl;
    upx[ch][0] = p0; upx[ch][1] = p1; upx[ch][2] = p2; upx[ch][3] = p3;
    upx[ch][4] = p4; upx[ch][5] = p5; upx[ch][6] = p6; upx[ch][7] = p7;
    labp[ch >> 2] |= (unsigned)cl << (8 * (ch & 3));

    if (ch + 1 < SCH) {                 // prefetch next chunk
      const size_t p = base + (size_t)(ch + 1) * 64 + l;
      const float4* ep = embv + p * 4;
      c0 = ep[0]; c1 = ep[1]; c2 = ep[2]; c3 = ep[3];
      cl = lab[p];
    }

    #pragma unroll
    for (int s = 0; s < 4; ++s) {
      const int4* lp = (const int4*)&slab[w][s * 16 + 8 * h];
      const int4 la = lp[0], lb = lp[1];
      const short ONE = (short)0x3F80;  // bf16 1.0
      short8 av;
      av[0] = (la.x == m) ? ONE : (short)0; av[1] = (la.y == m) ? ONE : (short)0;
      av[2] = (la.z == m) ? ONE : (short)0; av[3] = (la.w == m) ? ONE : (short)0;
      av[4] = (lb.x == m) ? ONE : (short)0; av[5] = (lb.y == m) ? ONE : (short)0;
      av[6] = (lb.z == m) ? ONE : (short)0; av[7] = (lb.w == m) ? ONE : (short)0;

      short8 bv;
      if (m < CH) {
        const uint4* fp = (const uint4*)&smem[w][m >> 1][s * 16 + 8 * h];
        const uint4 u0 = fp[0], u1 = fp[1];
        const unsigned sh = (unsigned)(m & 1) * 16u;
        bv[0] = (short)((u0.x >> sh) & 0xFFFFu); bv[1] = (short)((u0.y >> sh) & 0xFFFFu);
        bv[2] = (short)((u0.z >> sh) & 0xFFFFu); bv[3] = (short)((u0.w >> sh) & 0xFFFFu);
        bv[4] = (short)((u1.x >> sh) & 0xFFFFu); bv[5] = (short)((u1.y >> sh) & 0xFFFFu);
        bv[6] = (short)((u1.z >> sh) & 0xFFFFu); bv[7] = (short)((u1.w >> sh) & 0xFFFFu);
      } else {
        const short cv = (m == CH) ? ONE : (short)0;   // col 16 = ones -> counts
        #pragma unroll
        for (int e = 0; e < 8; ++e) bv[e] = cv;
      }
      acc = __builtin_amdgcn_mfma_f32_32x32x16_bf16(av, bv, acc, 0, 0, 0);
    }
  }

  if (m < 17) {
    #pragma unroll
    for (int r = 0; r < 16; ++r) {
      const int row = (r & 3) + 8 * (r >> 2) + 4 * h;   // verified C/D layout
      sred[w][row * 17 + m] = acc[r];
    }
  }
  __syncthreads();
  for (int i = t; i < KC * 17; i += TPB) {
    float v = 0.f;
    #pragma unroll
    for (int w2 = 0; w2 < 8; ++w2) v += sred[w2][i];
    ws[WS_PART + (size_t)blockIdx.x * 544 + i] = v;
  }

  grid.sync();

  // ---------------- Phase B: centroids + push + reg (blocks 0..7) ----------------
  if (blockIdx.x < NB) {
    const int bb = blockIdx.x;
    for (int i = t; i < KC * 17; i += TPB) {
      float s = 0.f;
      const float* p0 = ws + WS_PART + (size_t)(bb * BPI) * 544 + i;
      for (int p = 0; p < BPI; ++p) s += p0[(size_t)p * 544];
      sums_s[i] = s;
    }
    __syncthreads();
    if (t < KC) validf[t] = (sums_s[t * 17 + 16] > 0.f) ? 1.f : 0.f;

    const int k = t & 31, c = t >> 5;   // t in [0,512) covers all (k,c)
    const float cnt = sums_s[k * 17 + 16];
    const float ce  = (cnt > 0.f) ? sums_s[k * 17 + c] / cnt : 0.f;
    cs[c * KC + k] = ce;
    ws[WS_CEN + (size_t)bb * CH * KC + c * KC + k] = ce;
    const float regacc = ce * ce;
    __syncthreads();

    float pushacc = 0.f;
    for (int p = t; p < KC * KC; p += TPB) {
      const int i = p >> 5, j = p & 31;
      if (i < j && validf[i] > 0.f && validf[j] > 0.f) {
        float pd = 0.f;
        #pragma unroll
        for (int cc = 0; cc < CH; ++cc)
          pd += fabsf(cs[cc * KC + i] - cs[cc * KC + j]);
        const float hi = 0.25f - pd;
        if (hi > 0.f) pushacc += hi * hi;
      }
    }

    float v = pushacc;
    #pragma unroll
    for (int off = 32; off; off >>= 1) v += __shfl_down(v, off, 64);
    if (l == 0) red8[w] = v;
    __syncthreads();
    float pushsum = 0.f;
    if (t == 0) { for (int i = 0; i < 8; ++i) pushsum += red8[i]; }
    __syncthreads();

    v = regacc;
    #pragma unroll
    for (int off = 32; off; off >>= 1) v += __shfl_down(v, off, 64);
    if (l == 0) red8[w] = v;
    __syncthreads();

    if (t == 0) {
      float regsum = 0.f;
      for (int i = 0; i < 8; ++i) regsum += red8[i];
      float nv = 0.f;
      for (int i = 0; i < KC; ++i) nv += validf[i];
      const float ncomp = nv * (nv - 1.f) * 0.5f;
      const float push  = (nv >= 2.f) ? pushsum / fmaxf(ncomp, 1.f) : 0.f;
      const float reg   = regsum / fmaxf(nv * (float)CH, 1.f);
      ws[WS_PR + bb] = push + 1e-4f * reg;
    }
  }

  grid.sync();

  // ---------------- Phase C: pull loss from retained registers ----------------
  for (int i = t; i < CH * KC; i += TPB)
    pcent[i] = ws[WS_CEN + (size_t)b * CH * KC + i];
  __syncthreads();

  float pacc = 0.f;
  #pragma unroll
  for (int ch = 0; ch < SCH; ++ch) {
    const int L = (int)((labp[ch >> 2] >> (8 * (ch & 3))) & 31u);
    float d = 0.f;
    #pragma unroll
    for (int pr = 0; pr < 8; ++pr) {
      const unsigned u = upx[ch][pr];
      const float lo = __builtin_bit_cast(float, u << 16);
      const float hi = __builtin_bit_cast(float, u & 0xFFFF0000u);
      d += fabsf(lo - pcent[(2 * pr) * KC + L]);
      d += fabsf(hi - pcent[(2 * pr + 1) * KC + L]);
    }
    pacc += d * d;
  }
  {
    float v = pacc;
    #pragma unroll
    for (int off = 32; off; off >>= 1) v += __shfl_down(v, off, 64);
    if (l == 0) red8[w] = v;
    __syncthreads();
    if (t == 0) {
      float s = 0.f;
      for (int i = 0; i < 8; ++i) s += red8[i];
      ws[WS_PLP + blockIdx.x] = s;
    }
  }

  grid.sync();

  // ---------------- Phase D: final reduce (block 0) ----------------
  if (blockIdx.x == 0) {
    __shared__ float simg[NB];
    float v = (t < NBLK) ? ws[WS_PLP + t] : 0.f;   // 32 partials per image
    #pragma unroll
    for (int off = 16; off; off >>= 1) v += __shfl_down(v, off, 32);
    if (t < NBLK && (t & 31) == 0) simg[t >> 5] = v;
    __syncthreads();
    if (t == 0) {
      float s = 0.f;
      for (int bb = 0; bb < NB; ++bb)
        s += ws[WS_PR + bb] + simg[bb] * (1.f / (float)NPI);
      out[0] = s * (1.f / (float)NB);
    }
  }
}

extern "C" void kernel_launch(void* const* d_in, const int* in_sizes, int n_in,
                              void* d_out, int out_size, void* d_ws, size_t ws_size,
                              hipStream_t stream) {
  const float4* emb = (const float4*)d_in[0];
  const int*    labp = (const int*)d_in[1];
  float* wsp  = (float*)d_ws;
  float* outp = (float*)d_out;
  void* args[] = {(void*)&emb, (void*)&labp, (void*)&wsp, (void*)&outp};
  hipLaunchCooperativeKernel((const void*)fused_kernel, dim3(NBLK), dim3(TPB),
                             args, 0, stream);
}

// Round 5
// 144.978 us; speedup vs baseline: 1.1761x; 1.1761x over previous
//
#include <hip/hip_runtime.h>
#include <hip/hip_cooperative_groups.h>

#define KC 32
#define CH 16
#define NB 8
#define NPI (512*512)
#define TPB 512               // 8 waves
#define NBLK 256              // 1 block per CU -> cooperative launch always fits
#define BPI (NBLK/NB)         // 32 blocks per image
#define PPB (NPI/BPI)         // 8192 px per block
#define SPW (PPB/8)           // 1024 px per wave
#define SCH (SPW/64)          // 16 chunks of 64 px

// ws layout (floats); every cell written before read each call -> no pre-zero
#define WS_PART 0                          // [256][544] per-block segsum partials
#define WS_CEN (WS_PART + NBLK*544)        // [8][16][32] centroids [c][k]
#define WS_PR  (WS_CEN + NB*CH*KC)         // [8] push + 1e-4*reg
#define WS_PLP (WS_PR + NB)                // [256] per-block pull partials

typedef float f32x16 __attribute__((ext_vector_type(16)));
typedef short short8 __attribute__((ext_vector_type(8)));

__device__ __forceinline__ unsigned short f2bf(float x) {
  unsigned u = __builtin_bit_cast(unsigned, x);
  u += 0x7FFFu + ((u >> 16) & 1u);          // RNE to bf16
  return (unsigned short)(u >> 16);
}
__device__ __forceinline__ unsigned packbf(float lo, float hi) {
  return (unsigned)f2bf(lo) | ((unsigned)f2bf(hi) << 16);
}

__global__ __launch_bounds__(TPB, 2) void fused_kernel(
    const float4* __restrict__ embv, const int* __restrict__ lab,
    float* __restrict__ ws, float* __restrict__ out) {
  __shared__ unsigned smem[8][8][68];   // per-wave bf16x2 staging, stride-68 pad
  __shared__ int      slab[8][64];
  __shared__ float    sred[8][KC * 17];
  __shared__ float    pcent[CH * KC];   // phase C centroids [c][k]
  __shared__ float    sums_s[KC * 17];  // phase B
  __shared__ float    cs[CH * KC];      // phase B centroids [c][k]
  __shared__ float    validf[KC];
  __shared__ float    red8[8];
  __shared__ float    simg[NB];

  const int t = threadIdx.x, w = t >> 6, l = t & 63;
  const int h = l >> 5;                 // k-half of MFMA operands
  const int m = l & 31;                 // A row (label) / B col (channel|count)
  const int b = blockIdx.x / BPI, blk = blockIdx.x % BPI;
  const size_t base = (size_t)b * NPI + (size_t)blk * PPB + (size_t)w * SPW;

  cooperative_groups::grid_group grid = cooperative_groups::this_grid();

  f32x16 acc;
  #pragma unroll
  for (int i = 0; i < 16; ++i) acc[i] = 0.f;

  float4 c0, c1, c2, c3; int cl;
  {
    const float4* ep = embv + (base + l) * 4;
    c0 = ep[0]; c1 = ep[1]; c2 = ep[2]; c3 = ep[3];
    cl = lab[base + l];
  }

  // ---------------- Phase A: segment-sum via onehot^T * emb (MFMA) ----------------
  for (int ch = 0; ch < SCH; ++ch) {
    smem[w][0][l] = packbf(c0.x, c0.y);
    smem[w][1][l] = packbf(c0.z, c0.w);
    smem[w][2][l] = packbf(c1.x, c1.y);
    smem[w][3][l] = packbf(c1.z, c1.w);
    smem[w][4][l] = packbf(c2.x, c2.y);
    smem[w][5][l] = packbf(c2.z, c2.w);
    smem[w][6][l] = packbf(c3.x, c3.y);
    smem[w][7][l] = packbf(c3.z, c3.w);
    slab[w][l] = cl;

    if (ch + 1 < SCH) {                 // prefetch next chunk
      const size_t p = base + (size_t)(ch + 1) * 64 + l;
      const float4* ep = embv + p * 4;
      c0 = ep[0]; c1 = ep[1]; c2 = ep[2]; c3 = ep[3];
      cl = lab[p];
    }

    #pragma unroll
    for (int s = 0; s < 4; ++s) {
      const int4* lp = (const int4*)&slab[w][s * 16 + 8 * h];
      const int4 la = lp[0], lb = lp[1];
      const short ONE = (short)0x3F80;  // bf16 1.0
      short8 av;
      av[0] = (la.x == m) ? ONE : (short)0; av[1] = (la.y == m) ? ONE : (short)0;
      av[2] = (la.z == m) ? ONE : (short)0; av[3] = (la.w == m) ? ONE : (short)0;
      av[4] = (lb.x == m) ? ONE : (short)0; av[5] = (lb.y == m) ? ONE : (short)0;
      av[6] = (lb.z == m) ? ONE : (short)0; av[7] = (lb.w == m) ? ONE : (short)0;

      short8 bv;
      if (m < CH) {
        const uint4* fp = (const uint4*)&smem[w][m >> 1][s * 16 + 8 * h];
        const uint4 u0 = fp[0], u1 = fp[1];
        const unsigned sh = (unsigned)(m & 1) * 16u;
        bv[0] = (short)((u0.x >> sh) & 0xFFFFu); bv[1] = (short)((u0.y >> sh) & 0xFFFFu);
        bv[2] = (short)((u0.z >> sh) & 0xFFFFu); bv[3] = (short)((u0.w >> sh) & 0xFFFFu);
        bv[4] = (short)((u1.x >> sh) & 0xFFFFu); bv[5] = (short)((u1.y >> sh) & 0xFFFFu);
        bv[6] = (short)((u1.z >> sh) & 0xFFFFu); bv[7] = (short)((u1.w >> sh) & 0xFFFFu);
      } else {
        const short cv = (m == CH) ? ONE : (short)0;   // col 16 = ones -> counts
        #pragma unroll
        for (int e = 0; e < 8; ++e) bv[e] = cv;
      }
      acc = __builtin_amdgcn_mfma_f32_32x32x16_bf16(av, bv, acc, 0, 0, 0);
    }
  }

  if (m < 17) {
    #pragma unroll
    for (int r = 0; r < 16; ++r) {
      const int row = (r & 3) + 8 * (r >> 2) + 4 * h;   // verified C/D layout
      sred[w][row * 17 + m] = acc[r];
    }
  }
  __syncthreads();
  for (int i = t; i < KC * 17; i += TPB) {
    float v = 0.f;
    #pragma unroll
    for (int w2 = 0; w2 < 8; ++w2) v += sred[w2][i];
    ws[WS_PART + (size_t)blockIdx.x * 544 + i] = v;
  }

  grid.sync();

  // ---------------- Phase B: centroids + push + reg (blocks 0..7) ----------------
  if (blockIdx.x < NB) {
    const int bb = blockIdx.x;
    for (int i = t; i < KC * 17; i += TPB) {
      float s = 0.f;
      const float* p0 = ws + WS_PART + (size_t)(bb * BPI) * 544 + i;
      for (int p = 0; p < BPI; ++p) s += p0[(size_t)p * 544];
      sums_s[i] = s;
    }
    __syncthreads();
    if (t < KC) validf[t] = (sums_s[t * 17 + 16] > 0.f) ? 1.f : 0.f;

    const int k = t & 31, c = t >> 5;   // t in [0,512) covers all (k,c)
    const float cnt = sums_s[k * 17 + 16];
    const float ce  = (cnt > 0.f) ? sums_s[k * 17 + c] / cnt : 0.f;
    cs[c * KC + k] = ce;
    ws[WS_CEN + (size_t)bb * CH * KC + c * KC + k] = ce;
    const float regacc = ce * ce;
    __syncthreads();

    float pushacc = 0.f;
    for (int p = t; p < KC * KC; p += TPB) {
      const int i = p >> 5, j = p & 31;
      if (i < j && validf[i] > 0.f && validf[j] > 0.f) {
        float pd = 0.f;
        #pragma unroll
        for (int cc = 0; cc < CH; ++cc)
          pd += fabsf(cs[cc * KC + i] - cs[cc * KC + j]);
        const float hi = 0.25f - pd;
        if (hi > 0.f) pushacc += hi * hi;
      }
    }

    float v = pushacc;
    #pragma unroll
    for (int off = 32; off; off >>= 1) v += __shfl_down(v, off, 64);
    if (l == 0) red8[w] = v;
    __syncthreads();
    float pushsum = 0.f;
    if (t == 0) { for (int i = 0; i < 8; ++i) pushsum += red8[i]; }
    __syncthreads();

    v = regacc;
    #pragma unroll
    for (int off = 32; off; off >>= 1) v += __shfl_down(v, off, 64);
    if (l == 0) red8[w] = v;
    __syncthreads();

    if (t == 0) {
      float regsum = 0.f;
      for (int i = 0; i < 8; ++i) regsum += red8[i];
      float nv = 0.f;
      for (int i = 0; i < KC; ++i) nv += validf[i];
      const float ncomp = nv * (nv - 1.f) * 0.5f;
      const float push  = (nv >= 2.f) ? pushsum / fmaxf(ncomp, 1.f) : 0.f;
      const float reg   = regsum / fmaxf(nv * (float)CH, 1.f);
      ws[WS_PR + bb] = push + 1e-4f * reg;
    }
  }

  grid.sync();

  // ---------------- Phase C: pull loss, second streaming pass (fp32 exact) ----------------
  for (int i = t; i < CH * KC; i += TPB)
    pcent[i] = ws[WS_CEN + (size_t)b * CH * KC + i];
  __syncthreads();

  float pacc = 0.f;
  for (int it = 0; it < SCH; it += 2) {
    const size_t p0 = base + (size_t)it * 64 + l;
    const size_t p1 = p0 + 64;
    const int L0 = lab[p0], L1 = lab[p1];
    const float4 a0 = embv[p0*4+0], a1 = embv[p0*4+1], a2 = embv[p0*4+2], a3 = embv[p0*4+3];
    const float4 b0 = embv[p1*4+0], b1 = embv[p1*4+1], b2 = embv[p1*4+2], b3 = embv[p1*4+3];
    float d0 = 0.f, d1 = 0.f;
    d0 += fabsf(a0.x - pcent[ 0*KC + L0]); d0 += fabsf(a0.y - pcent[ 1*KC + L0]);
    d0 += fabsf(a0.z - pcent[ 2*KC + L0]); d0 += fabsf(a0.w - pcent[ 3*KC + L0]);
    d0 += fabsf(a1.x - pcent[ 4*KC + L0]); d0 += fabsf(a1.y - pcent[ 5*KC + L0]);
    d0 += fabsf(a1.z - pcent[ 6*KC + L0]); d0 += fabsf(a1.w - pcent[ 7*KC + L0]);
    d0 += fabsf(a2.x - pcent[ 8*KC + L0]); d0 += fabsf(a2.y - pcent[ 9*KC + L0]);
    d0 += fabsf(a2.z - pcent[10*KC + L0]); d0 += fabsf(a2.w - pcent[11*KC + L0]);
    d0 += fabsf(a3.x - pcent[12*KC + L0]); d0 += fabsf(a3.y - pcent[13*KC + L0]);
    d0 += fabsf(a3.z - pcent[14*KC + L0]); d0 += fabsf(a3.w - pcent[15*KC + L0]);
    d1 += fabsf(b0.x - pcent[ 0*KC + L1]); d1 += fabsf(b0.y - pcent[ 1*KC + L1]);
    d1 += fabsf(b0.z - pcent[ 2*KC + L1]); d1 += fabsf(b0.w - pcent[ 3*KC + L1]);
    d1 += fabsf(b1.x - pcent[ 4*KC + L1]); d1 += fabsf(b1.y - pcent[ 5*KC + L1]);
    d1 += fabsf(b1.z - pcent[ 6*KC + L1]); d1 += fabsf(b1.w - pcent[ 7*KC + L1]);
    d1 += fabsf(b2.x - pcent[ 8*KC + L1]); d1 += fabsf(b2.y - pcent[ 9*KC + L1]);
    d1 += fabsf(b2.z - pcent[10*KC + L1]); d1 += fabsf(b2.w - pcent[11*KC + L1]);
    d1 += fabsf(b3.x - pcent[12*KC + L1]); d1 += fabsf(b3.y - pcent[13*KC + L1]);
    d1 += fabsf(b3.z - pcent[14*KC + L1]); d1 += fabsf(b3.w - pcent[15*KC + L1]);
    pacc += d0 * d0 + d1 * d1;
  }
  {
    float v = pacc;
    #pragma unroll
    for (int off = 32; off; off >>= 1) v += __shfl_down(v, off, 64);
    if (l == 0) red8[w] = v;
    __syncthreads();
    if (t == 0) {
      float s = 0.f;
      for (int i = 0; i < 8; ++i) s += red8[i];
      ws[WS_PLP + blockIdx.x] = s;
    }
  }

  grid.sync();

  // ---------------- Phase D: final reduce (block 0) ----------------
  if (blockIdx.x == 0) {
    float v = (t < NBLK) ? ws[WS_PLP + t] : 0.f;   // 32 partials per image
    #pragma unroll
    for (int off = 16; off; off >>= 1) v += __shfl_down(v, off, 32);
    if (t < NBLK && (t & 31) == 0) simg[t >> 5] = v;
    __syncthreads();
    if (t == 0) {
      float s = 0.f;
      for (int bb = 0; bb < NB; ++bb)
        s += ws[WS_PR + bb] + simg[bb] * (1.f / (float)NPI);
      out[0] = s * (1.f / (float)NB);
    }
  }
}

extern "C" void kernel_launch(void* const* d_in, const int* in_sizes, int n_in,
                              void* d_out, int out_size, void* d_ws, size_t ws_size,
                              hipStream_t stream) {
  const float4* emb = (const float4*)d_in[0];
  const int*    labp = (const int*)d_in[1];
  float* wsp  = (float*)d_ws;
  float* outp = (float*)d_out;
  void* args[] = {(void*)&emb, (void*)&labp, (void*)&wsp, (void*)&outp};
  hipLaunchCooperativeKernel((const void*)fused_kernel, dim3(NBLK), dim3(TPB),
                             args, 0, stream);
}